// Round 9
// baseline (246.222 us; speedup 1.0000x reference)
//
#include <hip/hip_runtime.h>
#include <hip/hip_bf16.h>
#include <math.h>

#define N_NODES 8192
#define N_EDGES 131072
#define NGRP 16
#define NLAY 2
#define NELM 4
constexpr float INV_AVG = 1.0f / 16.0f;
constexpr float PI_F = 3.14159265358979323846f;

// swizzled bf16 MFMA B-fragment radial weights: per layer 10240 shorts
#define SWZ_PER_L 10240
#define SWZ_N     20480
// smallw layout (fp32): PROD@0(32) RO0@32(64) RO1A@96(1024) RO1B@1120(16)
#define SM_PROD 0
#define SM_RO0  32
#define SM_RO1A 96
#define SM_RO1B 1120
#define SM_N    1136

typedef __hip_bfloat16 bf16;
typedef __attribute__((ext_vector_type(8))) short bf16x8;
typedef __attribute__((ext_vector_type(4))) float f32x4;

__device__ __forceinline__ float silu_f(float x){ return x / (1.0f + __expf(-x)); }
__device__ __forceinline__ float bfbits2f(unsigned short u){
  return __uint_as_float(((unsigned)u) << 16);
}
__device__ __forceinline__ void unpack2(unsigned u, float& lo, float& hi){
  lo = __uint_as_float(u << 16);
  hi = __uint_as_float(u & 0xffff0000u);
}
__device__ __forceinline__ short f2bs(float v){
  union { bf16 b; short s; } u; u.b = __float2bfloat16(v); return u.s;
}
// dtype-agnostic element load: fl==1 -> buffer is bf16, else fp32
__device__ __forceinline__ float ldf2(const void* p, int i, int fl){
  if (fl) return bfbits2f(((const unsigned short*)p)[i]);
  return ((const float*)p)[i];
}
// inline dtype detection: same 256-B pos window as old k_detect (deterministic)
__device__ __forceinline__ int detect_flag(const void* pos){
  const uint4* p = (const uint4*)pos;
  bool bad = false;
#pragma unroll
  for (int i = 0; i < 16; i++){            // 16 uint4 = 64 dwords = 256 B
    uint4 v = p[i];
    unsigned a0 = v.x, a1 = v.y, a2 = v.z, a3 = v.w;
    float lo, hi;
    unpack2(a0, lo, hi); bad |= !(fabsf(lo) <= 1000.0f) || !(fabsf(hi) <= 1000.0f);
    unpack2(a1, lo, hi); bad |= !(fabsf(lo) <= 1000.0f) || !(fabsf(hi) <= 1000.0f);
    unpack2(a2, lo, hi); bad |= !(fabsf(lo) <= 1000.0f) || !(fabsf(hi) <= 1000.0f);
    unpack2(a3, lo, hi); bad |= !(fabsf(lo) <= 1000.0f) || !(fabsf(hi) <= 1000.0f);
  }
  return bad ? 0 : 1;   // 1 = bf16 world
}

// ======== k_pre: hist | radial swizzle | Wsc pack | h-init | smallw+flag ========
__global__ void __launch_bounds__(256) k_pre(const void* __restrict__ pos,
    const int* __restrict__ ei, const void* __restrict__ Wemb,
    const void* __restrict__ Wr1, const void* __restrict__ Wr2,
    const void* __restrict__ Wr3, const void* __restrict__ Wsc,
    const void* __restrict__ wprod, const void* __restrict__ wro0,
    const void* __restrict__ Wro1a, const void* __restrict__ wro1b,
    const int* __restrict__ types, int* __restrict__ deg,
    short* __restrict__ swz, unsigned short* __restrict__ Wscb,
    float* __restrict__ smallw, float* __restrict__ h0, int* __restrict__ flagbuf){
  int bid = blockIdx.x, t = threadIdx.x;
  if (bid < 512){                                   // hist
    int e = bid*256 + t;
    atomicAdd(&deg[ei[N_EDGES + e]], 1);
    return;
  }
  if (bid < 592){                                   // radial weight swizzle
    int fl = detect_flag(pos);
    int i = (bid - 512)*256 + t;                    // < 20480
    int l = i / SWZ_PER_L, w = i % SWZ_PER_L;
    float v;
    if (w < 2048){
      int tt = w >> 9, q = (w >> 7) & 3, n = (w >> 3) & 15, j = w & 7;
      int k = q*8 + j;
      v = (k < 8) ? ldf2(Wr1, l*512 + k*64 + tt*16 + n, fl) : 0.0f;
    } else if (w < 6144){
      int w2 = w - 2048;
      int nt = w2 >> 10, kt = (w2 >> 9) & 1, q = (w2 >> 7) & 3, n = (w2 >> 3) & 15, j = w2 & 7;
      int k = kt*32 + q*8 + j;
      v = ldf2(Wr2, l*4096 + k*64 + nt*16 + n, fl);
    } else {
      int w3 = w - 6144;
      int nt = w3 >> 10, kt = (w3 >> 9) & 1, q = (w3 >> 7) & 3, n = (w3 >> 3) & 15, j = w3 & 7;
      int k = kt*32 + q*8 + j;
      v = ldf2(Wr3, l*4096 + k*64 + nt*16 + n, fl);
    }
    swz[i] = f2bs(v);
    return;
  }
  if (bid < 720){                                   // Wsc -> bf16 pack
    int fl = detect_flag(pos);
    int j = (bid - 592)*256 + t;                    // < 32768
    Wscb[j] = (unsigned short)f2bs(ldf2(Wsc, j, fl));
    return;
  }
  if (bid < 2768){                                  // h init
    int fl = detect_flag(pos);
    int i = (bid - 720)*256 + t;                    // < 524288
    int n = i >> 6, c = i & 63;
    h0[i] = ldf2(Wemb, types[n]*64 + c, fl);
    return;
  }
  {                                                 // smallw + flag (1 block)
    int fl = detect_flag(pos);
    if (t == 0) flagbuf[0] = fl;
    for (int j = t; j < SM_N; j += 256){
      float v;
      if (j < 32)        v = ldf2(wprod, j, fl);
      else if (j < 96)   v = ldf2(wro0,  j - 32, fl);
      else if (j < 1120) v = ldf2(Wro1a, j - 96, fl);
      else               v = ldf2(wro1b, j - 1120, fl);
      smallw[j] = v;
    }
  }
}

// ---------------- CSR scan ----------------
__global__ void k_scan(const int* __restrict__ deg, int* __restrict__ row_start,
                       int* __restrict__ cursor){
  __shared__ int lds[1024];
  int t = threadIdx.x;
  int v[8]; int tot = 0;
#pragma unroll
  for (int k = 0; k < 8; k++){ v[k] = deg[t*8+k]; tot += v[k]; }
  lds[t] = tot; __syncthreads();
  for (int off = 1; off < 1024; off <<= 1){
    int x = (t >= off) ? lds[t-off] : 0;
    __syncthreads();
    lds[t] += x;
    __syncthreads();
  }
  int base = lds[t] - tot;
#pragma unroll
  for (int k = 0; k < 8; k++){ row_start[t*8+k] = base; cursor[t*8+k] = base; base += v[k]; }
  if (t == 1023) row_start[N_NODES] = base;
}

// fill: slot -> src node and slot -> dst node
__global__ void k_fill(const int* __restrict__ ei, int* __restrict__ cursor,
                       int* __restrict__ sslot, int* __restrict__ dslot){
  int e = blockIdx.x * 256 + threadIdx.x;
  if (e < N_EDGES){
    int d = ei[N_EDGES + e];
    int slot = atomicAdd(&cursor[d], 1);
    sslot[slot] = ei[e];
    dslot[slot] = d;
  }
}

// ==== MFMA radial MLP + inline geometry + fused h[src] multiply -> G[slot,c] ====
#define ROWS 72
template<int WRITE_Y>
__global__ void __launch_bounds__(256) k_mlp(const void* __restrict__ pos,
        const int* __restrict__ sslot, const int* __restrict__ dslot,
        const int* __restrict__ flagbuf, const short* __restrict__ sw,
        const float* __restrict__ h_old, bf16* __restrict__ Gb,
        unsigned short* __restrict__ Yb){
  __shared__ short lds[4][16*ROWS];
  int tix = threadIdx.x;
  int wv = tix >> 6, lane = tix & 63;
  int q = lane >> 4, nn = lane & 15;
  int ebase = blockIdx.x*64 + wv*16;
  int fl = flagbuf[0];

  // geometry for slot ebase+nn (redundant across quads)
  int slot = ebase + nn;
  int s = sslot[slot], d = dslot[slot];
  float vx = ldf2(pos, d*3+0, fl) - ldf2(pos, s*3+0, fl);
  float vy = ldf2(pos, d*3+1, fl) - ldf2(pos, s*3+1, fl);
  float vz = ldf2(pos, d*3+2, fl) - ldf2(pos, s*3+2, fl);
  float r = sqrtf(vx*vx + vy*vy + vz*vz + 1e-12f);
  float ir = 1.0f / r;

  if (WRITE_Y && q == 0){
    float x = vx*ir, y = vy*ir, z = vz*ir;
    const float s3 = 1.7320508075688772f, s15 = 3.872983346207417f, s5 = 2.23606797749979f;
    const float s105 = 10.246950765959598f, s7 = 2.6457513110645907f;
    const float c35 = 2.091650066335189f, c21 = 1.6201851746019651f;
    float x2 = x*x, y2 = y*y, z2 = z*z;
    float ys[16] = {
      1.0f, s3*x, s3*y, s3*z,
      s15*x*y, s15*y*z, 0.5f*s5*(3.0f*z2-1.0f), s15*x*z,
      0.5f*s15*(x2-y2), c35*y*(3.0f*x2-y2), s105*x*y*z, c21*y*(5.0f*z2-1.0f),
      0.5f*s7*(5.0f*z2*z-3.0f*z), c21*x*(5.0f*z2-1.0f), 0.5f*s105*z*(x2-y2),
      c35*x*(x2-3.0f*y2) };
    union { bf16 b[16]; uint4 u[2]; } pk;
#pragma unroll
    for (int k = 0; k < 16; k++) pk.b[k] = __float2bfloat16(ys[k]);
    uint4* yp = (uint4*)(Yb + (size_t)slot*16);
    yp[0] = pk.u[0];
    yp[1] = pk.u[1];
  }

  float xc = r * 0.2f;
  float f = 0.0f;
  if (xc < 1.0f){
    float x3 = xc*xc*xc, x6 = x3*x3, x7 = x6*xc, x8 = x7*xc;
    f = 1.0f - 28.0f*x6 + 48.0f*x7 - 21.0f*x8;
  }
  float bs = 0.6324555320336759f * f * ir;
  float t0 = PI_F * r * 0.2f;
  float ef[8];
#pragma unroll
  for (int k = 0; k < 8; k++) ef[k] = bs * __sinf((float)(k+1) * t0);

  bf16x8 af1 = {0,0,0,0,0,0,0,0};
  if (q == 0){
#pragma unroll
    for (int j = 0; j < 8; j++) af1[j] = f2bs(ef[j]);
  }

  const bf16x8* S1 = (const bf16x8*)(sw);
  const bf16x8* S2 = (const bf16x8*)(sw + 2048);
  const bf16x8* S3 = (const bf16x8*)(sw + 6144);
  short* A = lds[wv];

  f32x4 acc[4];
#pragma unroll
  for (int t = 0; t < 4; t++){
    bf16x8 b = S1[t*64 + q*16 + nn];
    f32x4 z = {0.f,0.f,0.f,0.f};
    acc[t] = __builtin_amdgcn_mfma_f32_16x16x32_bf16(af1, b, z, 0, 0, 0);
  }
#pragma unroll
  for (int t = 0; t < 4; t++)
#pragma unroll
    for (int rg = 0; rg < 4; rg++)
      A[(q*4+rg)*ROWS + t*16 + nn] = f2bs(silu_f(acc[t][rg]));
  __syncthreads();

  bf16x8 a0 = *(const bf16x8*)&A[nn*ROWS + 0*32 + q*8];
  bf16x8 a1 = *(const bf16x8*)&A[nn*ROWS + 1*32 + q*8];
  __syncthreads();
#pragma unroll
  for (int t = 0; t < 4; t++){
    f32x4 z = {0.f,0.f,0.f,0.f};
    bf16x8 b0 = S2[t*128 + 0*64 + q*16 + nn];
    bf16x8 b1 = S2[t*128 + 1*64 + q*16 + nn];
    z = __builtin_amdgcn_mfma_f32_16x16x32_bf16(a0, b0, z, 0, 0, 0);
    z = __builtin_amdgcn_mfma_f32_16x16x32_bf16(a1, b1, z, 0, 0, 0);
    acc[t] = z;
  }
#pragma unroll
  for (int t = 0; t < 4; t++)
#pragma unroll
    for (int rg = 0; rg < 4; rg++)
      A[(q*4+rg)*ROWS + t*16 + nn] = f2bs(silu_f(acc[t][rg]));
  __syncthreads();

  a0 = *(const bf16x8*)&A[nn*ROWS + 0*32 + q*8];
  a1 = *(const bf16x8*)&A[nn*ROWS + 1*32 + q*8];
  __syncthreads();
#pragma unroll
  for (int t = 0; t < 4; t++){
    f32x4 z = {0.f,0.f,0.f,0.f};
    bf16x8 b0 = S3[t*128 + 0*64 + q*16 + nn];
    bf16x8 b1 = S3[t*128 + 1*64 + q*16 + nn];
    z = __builtin_amdgcn_mfma_f32_16x16x32_bf16(a0, b0, z, 0, 0, 0);
    z = __builtin_amdgcn_mfma_f32_16x16x32_bf16(a1, b1, z, 0, 0, 0);
    acc[t] = z;
  }
#pragma unroll
  for (int t = 0; t < 4; t++)
#pragma unroll
    for (int rg = 0; rg < 4; rg++)
      A[(q*4+rg)*ROWS + t*16 + nn] = f2bs(acc[t][rg]);
  __syncthreads();

  // G = bf16(Rw * h_old[src]) ; lane covers 16 channels of one slot row
  int row = lane >> 2, c4 = lane & 3;
  int src = sslot[ebase + row];
  const float4* hp = (const float4*)(h_old + (size_t)src*64 + c4*16);
  float4 h0 = hp[0], h1 = hp[1], h2 = hp[2], h3 = hp[3];
  float hval[16] = {h0.x,h0.y,h0.z,h0.w, h1.x,h1.y,h1.z,h1.w,
                    h2.x,h2.y,h2.z,h2.w, h3.x,h3.y,h3.z,h3.w};
  union { uint4 u[2]; unsigned short s[16]; } rw;
  rw.u[0] = *(const uint4*)&A[row*ROWS + c4*16];
  rw.u[1] = *(const uint4*)&A[row*ROWS + c4*16 + 8];
  union { bf16 b[16]; uint4 u[2]; } g;
#pragma unroll
  for (int kk = 0; kk < 16; kk++)
    g.b[kk] = __float2bfloat16(bfbits2f(rw.s[kk]) * hval[kk]);
  uint4* gp = (uint4*)(Gb + ((size_t)(ebase + row))*64 + c4*16);
  gp[0] = g.u[0];
  gp[1] = g.u[1];
}

// ======= node update + readout; gu<1> also writes the final output ==============
#define UNR 8
template<int LAYER_KIND>
__global__ void __launch_bounds__(256, 4) k_gu(const bf16* __restrict__ Gb,
        const float* __restrict__ h_old, float* __restrict__ h_new,
        const unsigned short* __restrict__ Yb, const int* __restrict__ row_start,
        const int* __restrict__ types, const unsigned short* __restrict__ Wscb,
        const float* __restrict__ prodw, const float* __restrict__ smallw,
        const int* __restrict__ batch, float* __restrict__ ene,
        int* __restrict__ ticket, const int* __restrict__ flagbuf,
        void* __restrict__ out){
  __shared__ float ebins[NGRP];
  __shared__ float hn_l[4][64];
  __shared__ int winner;
  int tix = threadIdx.x;
  if (tix < NGRP) ebins[tix] = 0.0f;
  __syncthreads();
  int wv = tix >> 6, lane = tix & 63;
  int n = __builtin_amdgcn_readfirstlane((blockIdx.x * 256 + tix) >> 6);
  {
    int beg = row_start[n], end = row_start[n+1];
    const unsigned short* G = (const unsigned short*)Gb;
    float acc[16];
#pragma unroll
    for (int s = 0; s < 16; s++) acc[s] = 0.0f;
    int last = end - 1;
    for (int it = beg; it < end; it += UNR){
      float gv[UNR];
      uint4 ya[UNR], yc[UNR];
#pragma unroll
      for (int k = 0; k < UNR; k++){
        int ic = min(it + k, last);
        gv[k] = bfbits2f(G[(size_t)ic*64 + lane]);
        const uint4* yp = (const uint4*)(Yb + (size_t)ic*16);
        ya[k] = yp[0];
        yc[k] = yp[1];
      }
#pragma unroll
      for (int k = 0; k < UNR; k++){
        float g = (it + k < end) ? gv[k] : 0.0f;
        float lo, hi;
        unpack2(ya[k].x, lo, hi); acc[0]  += g*lo; acc[1]  += g*hi;
        unpack2(ya[k].y, lo, hi); acc[2]  += g*lo; acc[3]  += g*hi;
        unpack2(ya[k].z, lo, hi); acc[4]  += g*lo; acc[5]  += g*hi;
        unpack2(ya[k].w, lo, hi); acc[6]  += g*lo; acc[7]  += g*hi;
        unpack2(yc[k].x, lo, hi); acc[8]  += g*lo; acc[9]  += g*hi;
        unpack2(yc[k].y, lo, hi); acc[10] += g*lo; acc[11] += g*hi;
        unpack2(yc[k].z, lo, hi); acc[12] += g*lo; acc[13] += g*hi;
        unpack2(yc[k].w, lo, hi); acc[14] += g*lo; acc[15] += g*hi;
      }
    }
#pragma unroll
    for (int s = 0; s < 16; s++) acc[s] *= INV_AVG;

    int ty = __builtin_amdgcn_readfirstlane(types[n]);
    const unsigned short* Ws = Wscb + (size_t)ty*4096;
    float sc = 0.0f;
#pragma unroll 8
    for (int c = 0; c < 64; c++)
      sc += h_old[(size_t)n*64 + c] * bfbits2f(Ws[c*64 + lane]);

    float inv0 = acc[0];
    float inv1 = acc[1]*acc[1] + acc[2]*acc[2] + acc[3]*acc[3];
    float inv2 = acc[4]*acc[4] + acc[5]*acc[5] + acc[6]*acc[6] + acc[7]*acc[7]
               + acc[8]*acc[8];
    float inv3 = acc[9]*acc[9] + acc[10]*acc[10] + acc[11]*acc[11] + acc[12]*acc[12]
               + acc[13]*acc[13] + acc[14]*acc[14] + acc[15]*acc[15];
    const float* wp = prodw + ty*4;
    float hn = inv0*wp[0] + inv1*wp[1] + inv2*wp[2] + inv3*wp[3] + sc;
    h_new[(size_t)n*64 + lane] = hn;

    float ev;
    if (LAYER_KIND == 0){
      float p = hn * smallw[SM_RO0 + lane];
#pragma unroll
      for (int off = 32; off >= 1; off >>= 1) p += __shfl_xor(p, off, 64);
      ev = p;
    } else {
      hn_l[wv][lane] = hn;
      int j = lane & 15;
      float pj = 0.0f;
#pragma unroll
      for (int c = 0; c < 64; c++)
        pj += hn_l[wv][c] * smallw[SM_RO1A + c*16 + j];
      float evj = silu_f(pj) * smallw[SM_RO1B + j];
      evj += __shfl_xor(evj, 8, 64);
      evj += __shfl_xor(evj, 4, 64);
      evj += __shfl_xor(evj, 2, 64);
      evj += __shfl_xor(evj, 1, 64);
      ev = evj;
    }
    if (lane == 0) atomicAdd(&ebins[batch[n]], ev);
  }
  __syncthreads();
  if (tix < NGRP){
    float v = ebins[tix];
    if (v != 0.0f) atomicAdd(&ene[tix], v);
  }
  if (LAYER_KIND == 1){
    __syncthreads();
    if (tix == 0){
      __threadfence();
      winner = (atomicAdd(ticket, 1) == (int)gridDim.x - 1) ? 1 : 0;
    }
    __syncthreads();
    if (winner && tix < NGRP){
      float v = atomicAdd(&ene[tix], 0.0f);   // device-scope read of final sum
      if (flagbuf[0]) ((bf16*)out)[tix] = __float2bfloat16(v);
      else            ((float*)out)[tix] = v;
    }
  }
}

static inline size_t rup(size_t x){ return (x + 255) & ~(size_t)255; }

extern "C" void kernel_launch(void* const* d_in, const int* in_sizes, int n_in,
                              void* d_out, int out_size, void* d_ws, size_t ws_size,
                              hipStream_t stream) {
  const void* pos   = d_in[0];
  const int*  types = (const int*)d_in[1];
  const int*  ei    = (const int*)d_in[2];
  const int*  batch = (const int*)d_in[3];
  const void* Wemb  = d_in[4];
  const void* Wr1   = d_in[5];
  const void* Wr2   = d_in[6];
  const void* Wr3   = d_in[7];
  const void* Wsc   = d_in[8];
  const void* wprod = d_in[9];
  const void* wro0  = d_in[10];
  const void* Wro1a = d_in[11];
  const void* wro1b = d_in[12];

  char* w = (char*)d_ws;
  // zero region (one memset): deg + ene + ticket
  int*   deg      = (int*)  w;                 // 8192 ints
  float* ene      = (float*)(w + 8192*4);      // 16 floats
  int*   ticket   = (int*)  (w + 8192*4 + 64); // 1 int
  w += rup(8192*4 + 128);
  int*   flagbuf  = (int*)  w; w += 256;
  short* swz      = (short*)w; w += rup((size_t)SWZ_N*2);
  unsigned short* Wscb = (unsigned short*)w; w += rup((size_t)32768*2);
  float* smallw   = (float*)w; w += rup((size_t)SM_N*4);
  int*   row_start= (int*)  w; w += rup((size_t)(N_NODES+1)*4);
  int*   cursor   = (int*)  w; w += rup((size_t)N_NODES*4);
  int*   sslot    = (int*)  w; w += rup((size_t)N_EDGES*4);
  int*   dslot    = (int*)  w; w += rup((size_t)N_EDGES*4);
  float* h0       = (float*)w; w += rup((size_t)N_NODES*64*4);
  float* h1       = (float*)w; w += rup((size_t)N_NODES*64*4);
  unsigned short* Yb = (unsigned short*)w; w += rup((size_t)N_EDGES*16*2);
  bf16*  Gb       = (bf16*) w; w += rup((size_t)N_EDGES*64*2);

  hipMemsetAsync(deg, 0, 8192*4 + 128, stream);

  k_pre<<<2769, 256, 0, stream>>>(pos, ei, Wemb, Wr1, Wr2, Wr3, Wsc, wprod,
                                  wro0, Wro1a, wro1b, types, deg, swz, Wscb,
                                  smallw, h0, flagbuf);
  k_scan<<<1, 1024, 0, stream>>>(deg, row_start, cursor);
  k_fill<<<N_EDGES/256, 256, 0, stream>>>(ei, cursor, sslot, dslot);

  float* hc = h0; float* hx = h1;
  for (int i = 0; i < NLAY; i++){
    if (i == 0)
      k_mlp<1><<<N_EDGES/64, 256, 0, stream>>>(pos, sslot, dslot, flagbuf,
          swz + i*SWZ_PER_L, hc, Gb, Yb);
    else
      k_mlp<0><<<N_EDGES/64, 256, 0, stream>>>(pos, sslot, dslot, flagbuf,
          swz + i*SWZ_PER_L, hc, Gb, Yb);
    if (i == 0)
      k_gu<0><<<(N_NODES*64)/256, 256, 0, stream>>>(Gb, hc, hx, Yb, row_start,
          types, Wscb + (size_t)i*16384, smallw + SM_PROD + i*16, smallw,
          batch, ene, ticket, flagbuf, d_out);
    else
      k_gu<1><<<(N_NODES*64)/256, 256, 0, stream>>>(Gb, hc, hx, Yb, row_start,
          types, Wscb + (size_t)i*16384, smallw + SM_PROD + i*16, smallw,
          batch, ene, ticket, flagbuf, d_out);
    float* tmp = hc; hc = hx; hx = tmp;
  }
}

// Round 10
// 242.114 us; speedup vs baseline: 1.0170x; 1.0170x over previous
//
#include <hip/hip_runtime.h>
#include <hip/hip_bf16.h>
#include <math.h>

#define N_NODES 8192
#define N_EDGES 131072
#define NGRP 16
#define NLAY 2
#define NELM 4
#define EPAD 32            // padding rows for staged over-read
constexpr float INV_AVG = 1.0f / 16.0f;
constexpr float PI_F = 3.14159265358979323846f;

// swizzled bf16 MFMA B-fragment radial weights: per layer 10240 shorts
#define SWZ_PER_L 10240
#define SWZ_N     20480
// smallw layout (fp32): PROD@0(32) RO0@32(64) RO1A@96(1024) RO1B@1120(16)
#define SM_PROD 0
#define SM_RO0  32
#define SM_RO1A 96
#define SM_RO1B 1120
#define SM_N    1136

typedef __hip_bfloat16 bf16;
typedef __attribute__((ext_vector_type(8))) short bf16x8;
typedef __attribute__((ext_vector_type(4))) float f32x4;

__device__ __forceinline__ float silu_f(float x){ return x / (1.0f + __expf(-x)); }
__device__ __forceinline__ float bfbits2f(unsigned short u){
  return __uint_as_float(((unsigned)u) << 16);
}
__device__ __forceinline__ void unpack2(unsigned u, float& lo, float& hi){
  lo = __uint_as_float(u << 16);
  hi = __uint_as_float(u & 0xffff0000u);
}
__device__ __forceinline__ short f2bs(float v){
  union { bf16 b; short s; } u; u.b = __float2bfloat16(v); return u.s;
}
// dtype-agnostic element load: fl==1 -> buffer is bf16, else fp32
__device__ __forceinline__ float ldf2(const void* p, int i, int fl){
  if (fl) return bfbits2f(((const unsigned short*)p)[i]);
  return ((const float*)p)[i];
}
// inline dtype detection: reads first 256 B of pos (deterministic verdict)
__device__ __forceinline__ int detect_flag(const void* pos){
  const uint4* p = (const uint4*)pos;
  bool bad = false;
#pragma unroll
  for (int i = 0; i < 16; i++){
    uint4 v = p[i];
    float lo, hi;
    unpack2(v.x, lo, hi); bad |= !(fabsf(lo) <= 1000.0f) || !(fabsf(hi) <= 1000.0f);
    unpack2(v.y, lo, hi); bad |= !(fabsf(lo) <= 1000.0f) || !(fabsf(hi) <= 1000.0f);
    unpack2(v.z, lo, hi); bad |= !(fabsf(lo) <= 1000.0f) || !(fabsf(hi) <= 1000.0f);
    unpack2(v.w, lo, hi); bad |= !(fabsf(lo) <= 1000.0f) || !(fabsf(hi) <= 1000.0f);
  }
  return bad ? 0 : 1;   // 1 = bf16 world
}

// ======== k_pre: hist | radial swizzle | Wsc fp32 copy | h-init | smallw+flag =====
__global__ void __launch_bounds__(256) k_pre(const void* __restrict__ pos,
    const int* __restrict__ ei, const void* __restrict__ Wemb,
    const void* __restrict__ Wr1, const void* __restrict__ Wr2,
    const void* __restrict__ Wr3, const void* __restrict__ Wsc,
    const void* __restrict__ wprod, const void* __restrict__ wro0,
    const void* __restrict__ Wro1a, const void* __restrict__ wro1b,
    const int* __restrict__ types, int* __restrict__ deg,
    short* __restrict__ swz, float* __restrict__ Wscf,
    float* __restrict__ smallw, float* __restrict__ h0, int* __restrict__ flagbuf){
  int bid = blockIdx.x, t = threadIdx.x;
  if (bid < 512){                                   // hist
    int e = bid*256 + t;
    atomicAdd(&deg[ei[N_EDGES + e]], 1);
    return;
  }
  if (bid < 592){                                   // radial weight swizzle
    int fl = detect_flag(pos);
    int i = (bid - 512)*256 + t;                    // < 20480
    int l = i / SWZ_PER_L, w = i % SWZ_PER_L;
    float v;
    if (w < 2048){
      int tt = w >> 9, q = (w >> 7) & 3, n = (w >> 3) & 15, j = w & 7;
      int k = q*8 + j;
      v = (k < 8) ? ldf2(Wr1, l*512 + k*64 + tt*16 + n, fl) : 0.0f;
    } else if (w < 6144){
      int w2 = w - 2048;
      int nt = w2 >> 10, kt = (w2 >> 9) & 1, q = (w2 >> 7) & 3, n = (w2 >> 3) & 15, j = w2 & 7;
      int k = kt*32 + q*8 + j;
      v = ldf2(Wr2, l*4096 + k*64 + nt*16 + n, fl);
    } else {
      int w3 = w - 6144;
      int nt = w3 >> 10, kt = (w3 >> 9) & 1, q = (w3 >> 7) & 3, n = (w3 >> 3) & 15, j = w3 & 7;
      int k = kt*32 + q*8 + j;
      v = ldf2(Wr3, l*4096 + k*64 + nt*16 + n, fl);
    }
    swz[i] = f2bs(v);
    return;
  }
  if (bid < 720){                                   // Wsc -> fp32 copy
    int fl = detect_flag(pos);
    int j = (bid - 592)*256 + t;                    // < 32768
    Wscf[j] = ldf2(Wsc, j, fl);
    return;
  }
  if (bid < 2768){                                  // h init
    int fl = detect_flag(pos);
    int i = (bid - 720)*256 + t;                    // < 524288
    int n = i >> 6, c = i & 63;
    h0[i] = ldf2(Wemb, types[n]*64 + c, fl);
    return;
  }
  {                                                 // smallw + flag (1 block)
    int fl = detect_flag(pos);
    if (t == 0) flagbuf[0] = fl;
    for (int j = t; j < SM_N; j += 256){
      float v;
      if (j < 32)        v = ldf2(wprod, j, fl);
      else if (j < 96)   v = ldf2(wro0,  j - 32, fl);
      else if (j < 1120) v = ldf2(Wro1a, j - 96, fl);
      else               v = ldf2(wro1b, j - 1120, fl);
      smallw[j] = v;
    }
  }
}

// ---------------- CSR scan ----------------
__global__ void k_scan(const int* __restrict__ deg, int* __restrict__ row_start,
                       int* __restrict__ cursor){
  __shared__ int lds[1024];
  int t = threadIdx.x;
  int v[8]; int tot = 0;
#pragma unroll
  for (int k = 0; k < 8; k++){ v[k] = deg[t*8+k]; tot += v[k]; }
  lds[t] = tot; __syncthreads();
  for (int off = 1; off < 1024; off <<= 1){
    int x = (t >= off) ? lds[t-off] : 0;
    __syncthreads();
    lds[t] += x;
    __syncthreads();
  }
  int base = lds[t] - tot;
#pragma unroll
  for (int k = 0; k < 8; k++){ row_start[t*8+k] = base; cursor[t*8+k] = base; base += v[k]; }
  if (t == 1023) row_start[N_NODES] = base;
}

// fill: slot -> src node and slot -> dst node
__global__ void k_fill(const int* __restrict__ ei, int* __restrict__ cursor,
                       int* __restrict__ sslot, int* __restrict__ dslot){
  int e = blockIdx.x * 256 + threadIdx.x;
  if (e < N_EDGES){
    int d = ei[N_EDGES + e];
    int slot = atomicAdd(&cursor[d], 1);
    sslot[slot] = ei[e];
    dslot[slot] = d;
  }
}

// ==== MFMA radial MLP + inline geometry + fused h[src] multiply -> G[slot,c] ====
#define ROWS 72
template<int WRITE_Y>
__global__ void __launch_bounds__(256) k_mlp(const void* __restrict__ pos,
        const int* __restrict__ sslot, const int* __restrict__ dslot,
        const int* __restrict__ flagbuf, const short* __restrict__ sw,
        const float* __restrict__ h_old, bf16* __restrict__ Gb,
        unsigned short* __restrict__ Yb){
  __shared__ short lds[4][16*ROWS];
  int tix = threadIdx.x;
  int wv = tix >> 6, lane = tix & 63;
  int q = lane >> 4, nn = lane & 15;
  int ebase = blockIdx.x*64 + wv*16;
  int fl = flagbuf[0];

  // geometry for slot ebase+nn (redundant across quads)
  int slot = ebase + nn;
  int s = sslot[slot], d = dslot[slot];
  float vx = ldf2(pos, d*3+0, fl) - ldf2(pos, s*3+0, fl);
  float vy = ldf2(pos, d*3+1, fl) - ldf2(pos, s*3+1, fl);
  float vz = ldf2(pos, d*3+2, fl) - ldf2(pos, s*3+2, fl);
  float r = sqrtf(vx*vx + vy*vy + vz*vz + 1e-12f);
  float ir = 1.0f / r;

  if (WRITE_Y && q == 0){
    float x = vx*ir, y = vy*ir, z = vz*ir;
    const float s3 = 1.7320508075688772f, s15 = 3.872983346207417f, s5 = 2.23606797749979f;
    const float s105 = 10.246950765959598f, s7 = 2.6457513110645907f;
    const float c35 = 2.091650066335189f, c21 = 1.6201851746019651f;
    float x2 = x*x, y2 = y*y, z2 = z*z;
    float ys[16] = {
      1.0f, s3*x, s3*y, s3*z,
      s15*x*y, s15*y*z, 0.5f*s5*(3.0f*z2-1.0f), s15*x*z,
      0.5f*s15*(x2-y2), c35*y*(3.0f*x2-y2), s105*x*y*z, c21*y*(5.0f*z2-1.0f),
      0.5f*s7*(5.0f*z2*z-3.0f*z), c21*x*(5.0f*z2-1.0f), 0.5f*s105*z*(x2-y2),
      c35*x*(x2-3.0f*y2) };
    union { bf16 b[16]; uint4 u[2]; } pk;
#pragma unroll
    for (int k = 0; k < 16; k++) pk.b[k] = __float2bfloat16(ys[k]);
    uint4* yp = (uint4*)(Yb + (size_t)slot*16);
    yp[0] = pk.u[0];
    yp[1] = pk.u[1];
  }

  float xc = r * 0.2f;
  float f = 0.0f;
  if (xc < 1.0f){
    float x3 = xc*xc*xc, x6 = x3*x3, x7 = x6*xc, x8 = x7*xc;
    f = 1.0f - 28.0f*x6 + 48.0f*x7 - 21.0f*x8;
  }
  float bs = 0.6324555320336759f * f * ir;
  float t0 = PI_F * r * 0.2f;
  float ef[8];
#pragma unroll
  for (int k = 0; k < 8; k++) ef[k] = bs * __sinf((float)(k+1) * t0);

  bf16x8 af1 = {0,0,0,0,0,0,0,0};
  if (q == 0){
#pragma unroll
    for (int j = 0; j < 8; j++) af1[j] = f2bs(ef[j]);
  }

  const bf16x8* S1 = (const bf16x8*)(sw);
  const bf16x8* S2 = (const bf16x8*)(sw + 2048);
  const bf16x8* S3 = (const bf16x8*)(sw + 6144);
  short* A = lds[wv];

  f32x4 acc[4];
#pragma unroll
  for (int t = 0; t < 4; t++){
    bf16x8 b = S1[t*64 + q*16 + nn];
    f32x4 z = {0.f,0.f,0.f,0.f};
    acc[t] = __builtin_amdgcn_mfma_f32_16x16x32_bf16(af1, b, z, 0, 0, 0);
  }
#pragma unroll
  for (int t = 0; t < 4; t++)
#pragma unroll
    for (int rg = 0; rg < 4; rg++)
      A[(q*4+rg)*ROWS + t*16 + nn] = f2bs(silu_f(acc[t][rg]));
  __syncthreads();

  bf16x8 a0 = *(const bf16x8*)&A[nn*ROWS + 0*32 + q*8];
  bf16x8 a1 = *(const bf16x8*)&A[nn*ROWS + 1*32 + q*8];
  __syncthreads();
#pragma unroll
  for (int t = 0; t < 4; t++){
    f32x4 z = {0.f,0.f,0.f,0.f};
    bf16x8 b0 = S2[t*128 + 0*64 + q*16 + nn];
    bf16x8 b1 = S2[t*128 + 1*64 + q*16 + nn];
    z = __builtin_amdgcn_mfma_f32_16x16x32_bf16(a0, b0, z, 0, 0, 0);
    z = __builtin_amdgcn_mfma_f32_16x16x32_bf16(a1, b1, z, 0, 0, 0);
    acc[t] = z;
  }
#pragma unroll
  for (int t = 0; t < 4; t++)
#pragma unroll
    for (int rg = 0; rg < 4; rg++)
      A[(q*4+rg)*ROWS + t*16 + nn] = f2bs(silu_f(acc[t][rg]));
  __syncthreads();

  a0 = *(const bf16x8*)&A[nn*ROWS + 0*32 + q*8];
  a1 = *(const bf16x8*)&A[nn*ROWS + 1*32 + q*8];
  __syncthreads();
#pragma unroll
  for (int t = 0; t < 4; t++){
    f32x4 z = {0.f,0.f,0.f,0.f};
    bf16x8 b0 = S3[t*128 + 0*64 + q*16 + nn];
    bf16x8 b1 = S3[t*128 + 1*64 + q*16 + nn];
    z = __builtin_amdgcn_mfma_f32_16x16x32_bf16(a0, b0, z, 0, 0, 0);
    z = __builtin_amdgcn_mfma_f32_16x16x32_bf16(a1, b1, z, 0, 0, 0);
    acc[t] = z;
  }
#pragma unroll
  for (int t = 0; t < 4; t++)
#pragma unroll
    for (int rg = 0; rg < 4; rg++)
      A[(q*4+rg)*ROWS + t*16 + nn] = f2bs(acc[t][rg]);
  __syncthreads();

  // G = bf16(Rw * h_old[src]) ; lane covers 16 channels of one slot row
  int row = lane >> 2, c4 = lane & 3;
  int src = sslot[ebase + row];
  const float4* hp = (const float4*)(h_old + (size_t)src*64 + c4*16);
  float4 h0 = hp[0], h1 = hp[1], h2 = hp[2], h3 = hp[3];
  float hval[16] = {h0.x,h0.y,h0.z,h0.w, h1.x,h1.y,h1.z,h1.w,
                    h2.x,h2.y,h2.z,h2.w, h3.x,h3.y,h3.z,h3.w};
  union { uint4 u[2]; unsigned short s[16]; } rw;
  rw.u[0] = *(const uint4*)&A[row*ROWS + c4*16];
  rw.u[1] = *(const uint4*)&A[row*ROWS + c4*16 + 8];
  union { bf16 b[16]; uint4 u[2]; } g;
#pragma unroll
  for (int kk = 0; kk < 16; kk++)
    g.b[kk] = __float2bfloat16(bfbits2f(rw.s[kk]) * hval[kk]);
  uint4* gp = (uint4*)(Gb + ((size_t)(ebase + row))*64 + c4*16);
  gp[0] = g.u[0];
  gp[1] = g.u[1];
}

// ======= node update + readout via LDS-staged sequential streams ================
// Per 32-edge chunk: 5 coalesced uint4 loads -> per-wave LDS region -> cheap
// LDS reads (G: 2-way-free ds_read_u16; Y: broadcast). Kills the serial
// load-wait chain that pinned R7-R9 k_gu.
template<int LAYER_KIND>
__global__ void __launch_bounds__(256, 4) k_gu(const bf16* __restrict__ Gb,
        const float* __restrict__ h_old, float* __restrict__ h_new,
        const unsigned short* __restrict__ Yb, const int* __restrict__ row_start,
        const int* __restrict__ types, const float* __restrict__ Wsc,
        const float* __restrict__ prodw, const float* __restrict__ smallw,
        const int* __restrict__ batch, float* __restrict__ ene,
        int* __restrict__ ticket, const int* __restrict__ flagbuf,
        void* __restrict__ out){
  __shared__ float ebins[NGRP];
  __shared__ float hn_l[4][64];
  __shared__ uint4 gstage[4][256];   // 4 KB per wave: 32 slots x 128 B
  __shared__ uint4 ystage[4][64];    // 1 KB per wave: 32 slots x 32 B
  __shared__ int winner;
  int tix = threadIdx.x;
  if (tix < NGRP) ebins[tix] = 0.0f;
  __syncthreads();
  int wv = tix >> 6, lane = tix & 63;
  int n = __builtin_amdgcn_readfirstlane((blockIdx.x * 256 + tix) >> 6);
  {
    int beg = row_start[n], end = row_start[n+1];
    float acc[16];
#pragma unroll
    for (int s = 0; s < 16; s++) acc[s] = 0.0f;
    uint4* gst = gstage[wv];
    uint4* yst = ystage[wv];
    for (int base = beg; base < end; base += 32){
      const uint4* gsrc = (const uint4*)Gb + (size_t)base*8;
      const uint4* ysrc = (const uint4*)Yb + (size_t)base*2;
      uint4 t0 = gsrc[lane];
      uint4 t1 = gsrc[64  + lane];
      uint4 t2 = gsrc[128 + lane];
      uint4 t3 = gsrc[192 + lane];
      uint4 t4 = ysrc[lane];
      gst[lane]       = t0;
      gst[64  + lane] = t1;
      gst[128 + lane] = t2;
      gst[192 + lane] = t3;
      yst[lane]       = t4;
      __builtin_amdgcn_wave_barrier();
      int m = min(32, end - base);
      const unsigned short* GS = (const unsigned short*)gst;
      const unsigned short* YS = (const unsigned short*)yst;
      for (int e = 0; e < m; e++){
        float g = bfbits2f(GS[e*64 + lane]);
        const uint4* yr = (const uint4*)(YS + (size_t)e*16);
        uint4 y0 = yr[0], y1 = yr[1];
        float lo, hi;
        unpack2(y0.x, lo, hi); acc[0]  += g*lo; acc[1]  += g*hi;
        unpack2(y0.y, lo, hi); acc[2]  += g*lo; acc[3]  += g*hi;
        unpack2(y0.z, lo, hi); acc[4]  += g*lo; acc[5]  += g*hi;
        unpack2(y0.w, lo, hi); acc[6]  += g*lo; acc[7]  += g*hi;
        unpack2(y1.x, lo, hi); acc[8]  += g*lo; acc[9]  += g*hi;
        unpack2(y1.y, lo, hi); acc[10] += g*lo; acc[11] += g*hi;
        unpack2(y1.z, lo, hi); acc[12] += g*lo; acc[13] += g*hi;
        unpack2(y1.w, lo, hi); acc[14] += g*lo; acc[15] += g*hi;
      }
      __builtin_amdgcn_wave_barrier();
    }
#pragma unroll
    for (int s = 0; s < 16; s++) acc[s] *= INV_AVG;

    int ty = __builtin_amdgcn_readfirstlane(types[n]);
    const float* Ws = Wsc + (size_t)ty*4096;
    float sc = 0.0f;
#pragma unroll 8
    for (int c = 0; c < 64; c++)
      sc += h_old[(size_t)n*64 + c] * Ws[c*64 + lane];  // h term wave-uniform -> s_load

    float inv0 = acc[0];
    float inv1 = acc[1]*acc[1] + acc[2]*acc[2] + acc[3]*acc[3];
    float inv2 = acc[4]*acc[4] + acc[5]*acc[5] + acc[6]*acc[6] + acc[7]*acc[7]
               + acc[8]*acc[8];
    float inv3 = acc[9]*acc[9] + acc[10]*acc[10] + acc[11]*acc[11] + acc[12]*acc[12]
               + acc[13]*acc[13] + acc[14]*acc[14] + acc[15]*acc[15];
    const float* wp = prodw + ty*4;
    float hn = inv0*wp[0] + inv1*wp[1] + inv2*wp[2] + inv3*wp[3] + sc;
    h_new[(size_t)n*64 + lane] = hn;

    float ev;
    if (LAYER_KIND == 0){
      float p = hn * smallw[SM_RO0 + lane];
#pragma unroll
      for (int off = 32; off >= 1; off >>= 1) p += __shfl_xor(p, off, 64);
      ev = p;
    } else {
      hn_l[wv][lane] = hn;
      int j = lane & 15;
      float pj = 0.0f;
#pragma unroll
      for (int c = 0; c < 64; c++)
        pj += hn_l[wv][c] * smallw[SM_RO1A + c*16 + j];
      float evj = silu_f(pj) * smallw[SM_RO1B + j];
      evj += __shfl_xor(evj, 8, 64);
      evj += __shfl_xor(evj, 4, 64);
      evj += __shfl_xor(evj, 2, 64);
      evj += __shfl_xor(evj, 1, 64);
      ev = evj;
    }
    if (lane == 0) atomicAdd(&ebins[batch[n]], ev);
  }
  __syncthreads();
  if (tix < NGRP){
    float v = ebins[tix];
    if (v != 0.0f) atomicAdd(&ene[tix], v);
  }
  if (LAYER_KIND == 1){
    __syncthreads();
    if (tix == 0){
      __threadfence();
      winner = (atomicAdd(ticket, 1) == (int)gridDim.x - 1) ? 1 : 0;
    }
    __syncthreads();
    if (winner && tix < NGRP){
      float v = atomicAdd(&ene[tix], 0.0f);   // device-scope read of final sum
      if (flagbuf[0]) ((bf16*)out)[tix] = __float2bfloat16(v);
      else            ((float*)out)[tix] = v;
    }
  }
}

static inline size_t rup(size_t x){ return (x + 255) & ~(size_t)255; }

extern "C" void kernel_launch(void* const* d_in, const int* in_sizes, int n_in,
                              void* d_out, int out_size, void* d_ws, size_t ws_size,
                              hipStream_t stream) {
  const void* pos   = d_in[0];
  const int*  types = (const int*)d_in[1];
  const int*  ei    = (const int*)d_in[2];
  const int*  batch = (const int*)d_in[3];
  const void* Wemb  = d_in[4];
  const void* Wr1   = d_in[5];
  const void* Wr2   = d_in[6];
  const void* Wr3   = d_in[7];
  const void* Wsc   = d_in[8];
  const void* wprod = d_in[9];
  const void* wro0  = d_in[10];
  const void* Wro1a = d_in[11];
  const void* wro1b = d_in[12];

  char* w = (char*)d_ws;
  // zero region (one memset): deg + ene + ticket
  int*   deg      = (int*)  w;                 // 8192 ints
  float* ene      = (float*)(w + 8192*4);      // 16 floats
  int*   ticket   = (int*)  (w + 8192*4 + 64); // 1 int
  w += rup(8192*4 + 128);
  int*   flagbuf  = (int*)  w; w += 256;
  short* swz      = (short*)w; w += rup((size_t)SWZ_N*2);
  float* Wscf     = (float*)w; w += rup((size_t)32768*4);
  float* smallw   = (float*)w; w += rup((size_t)SM_N*4);
  int*   row_start= (int*)  w; w += rup((size_t)(N_NODES+1)*4);
  int*   cursor   = (int*)  w; w += rup((size_t)N_NODES*4);
  int*   sslot    = (int*)  w; w += rup((size_t)N_EDGES*4);
  int*   dslot    = (int*)  w; w += rup((size_t)N_EDGES*4);
  float* h0       = (float*)w; w += rup((size_t)N_NODES*64*4);
  float* h1       = (float*)w; w += rup((size_t)N_NODES*64*4);
  unsigned short* Yb = (unsigned short*)w; w += rup((size_t)(N_EDGES+EPAD)*16*2);
  bf16*  Gb       = (bf16*) w; w += rup((size_t)(N_EDGES+EPAD)*64*2);

  hipMemsetAsync(deg, 0, 8192*4 + 128, stream);

  k_pre<<<2769, 256, 0, stream>>>(pos, ei, Wemb, Wr1, Wr2, Wr3, Wsc, wprod,
                                  wro0, Wro1a, wro1b, types, deg, swz, Wscf,
                                  smallw, h0, flagbuf);
  k_scan<<<1, 1024, 0, stream>>>(deg, row_start, cursor);
  k_fill<<<N_EDGES/256, 256, 0, stream>>>(ei, cursor, sslot, dslot);

  float* hc = h0; float* hx = h1;
  for (int i = 0; i < NLAY; i++){
    if (i == 0)
      k_mlp<1><<<N_EDGES/64, 256, 0, stream>>>(pos, sslot, dslot, flagbuf,
          swz + i*SWZ_PER_L, hc, Gb, Yb);
    else
      k_mlp<0><<<N_EDGES/64, 256, 0, stream>>>(pos, sslot, dslot, flagbuf,
          swz + i*SWZ_PER_L, hc, Gb, Yb);
    if (i == 0)
      k_gu<0><<<(N_NODES*64)/256, 256, 0, stream>>>(Gb, hc, hx, Yb, row_start,
          types, Wscf + (size_t)i*NELM*4096, smallw + SM_PROD + i*16, smallw,
          batch, ene, ticket, flagbuf, d_out);
    else
      k_gu<1><<<(N_NODES*64)/256, 256, 0, stream>>>(Gb, hc, hx, Yb, row_start,
          types, Wscf + (size_t)i*NELM*4096, smallw + SM_PROD + i*16, smallw,
          batch, ene, ticket, flagbuf, d_out);
    float* tmp = hc; hc = hx; hx = tmp;
  }
}